// Round 15
// baseline (195.586 us; speedup 1.0000x reference)
//
#include <hip/hip_runtime.h>
#include <hip/hip_bf16.h>

#define CS 384
#define CH 32
#define CZ 128
#define LL 384
#define NL 1536   // N*L
#define EPS 1e-5f

typedef float v4f __attribute__((ext_vector_type(4)));
typedef short s8v __attribute__((ext_vector_type(8)));          // 8 bf16 (MFMA A/B frag)
typedef unsigned short u8s __attribute__((ext_vector_type(8))); // 8 bf16 bits

static __device__ __forceinline__ unsigned short f2bf(float x) {
    unsigned int b = __float_as_uint(x);
    b += 0x7FFFu + ((b >> 16) & 1u);        // round-to-nearest-even
    return (unsigned short)(b >> 16);
}

// ---------------- Kernel 1: fused LN + matvec + pack Bf + M=A@Wo + pack Mf ---
// (identical to R14)
__global__ __launch_bounds__(256, 2) void k_prep(
    const float* __restrict__ s, const float* __restrict__ g, const float* __restrict__ be,
    const float* __restrict__ W1, const float* __restrict__ pb1,
    const float* __restrict__ W2, const float* __restrict__ pb2,
    const float* __restrict__ Wo,
    unsigned short* __restrict__ Bf, unsigned short* __restrict__ Mf)
{
    const int blk = blockIdx.x;     // 0..383
    const int r0  = blk * 4;
    const int t   = threadIdx.x;

    __shared__ float sn[4][392];
    __shared__ float Afl[4][CH];
    __shared__ __align__(16) float Msub[4 * 32 * 128];   // 64 KB

    // ---- Phase A: LayerNorm, wave w = row r0+w ----
    {
        const int w = t >> 6, lane = t & 63;
        const float* srow = s + (size_t)(r0 + w) * CS;
        float x[6];
        #pragma unroll
        for (int k = 0; k < 6; ++k) x[k] = srow[lane + k * 64];
        float p = x[0] + x[1] + x[2] + x[3] + x[4] + x[5];
        #pragma unroll
        for (int m = 1; m < 64; m <<= 1) p += __shfl_xor(p, m);
        const float mu = p * (1.0f / CS);
        float q = 0.f;
        #pragma unroll
        for (int k = 0; k < 6; ++k) { float d = x[k] - mu; q += d * d; }
        #pragma unroll
        for (int m = 1; m < 64; m <<= 1) q += __shfl_xor(q, m);
        const float rstd = rsqrtf(q * (1.0f / CS) + EPS);
        #pragma unroll
        for (int k = 0; k < 6; ++k) {
            const int c = lane + k * 64;
            sn[w][c] = (x[k] - mu) * rstd * g[c] + be[c];
        }
    }
    __syncthreads();

    // ---- Phase B: matvec, one output per thread ----
    {
        const int h = t & 31, mat = (t >> 5) & 1, rw = t >> 6;
        const float* W = mat ? W2 : W1;
        const float* snr = sn[rw];
        float acc = 0.f;
        #pragma unroll 8
        for (int c = 0; c < CS; ++c)
            acc += snr[c] * W[c * CH + h];
        acc += mat ? pb2[h] : pb1[h];
        if (!mat) {
            Afl[rw][h] = acc;
        } else {
            const int row = r0 + rw;
            const int n = row / LL, jr = row % LL;
            const int jt = jr >> 4, l16 = jr & 15;
            Bf[(((size_t)(n * 24 + jt)) * 64 + l16 + 16 * (h >> 3)) * 8 + (h & 7)] = f2bf(acc);
        }
    }
    __syncthreads();

    // ---- Phase C: M = Afl @ Wo ----
    const v4f* Wo4 = (const v4f*)Wo;       // 1024 v4f per c-row
    #pragma unroll
    for (int it = 0; it < 4; ++it) {
        const int col = t + it * 256;      // col = d*32 + zq
        v4f acc[4];
        #pragma unroll
        for (int r = 0; r < 4; ++r) acc[r] = (v4f)(0.f);
        #pragma unroll 8
        for (int c = 0; c < CH; ++c) {
            const v4f wv = Wo4[(size_t)c * 1024 + col];
            #pragma unroll
            for (int r = 0; r < 4; ++r)
                acc[r] += Afl[r][c] * wv;
        }
        #pragma unroll
        for (int r = 0; r < 4; ++r)
            *((v4f*)&Msub[r * 4096 + col * 4]) = acc[r];   // flat = r*4096 + d*128 + zq*4
    }
    __syncthreads();

    #pragma unroll
    for (int i = 0; i < 8; ++i) {
        const int item = t + i * 256;          // 0..2047
        const int l  = item & 63;
        const int zt = (item >> 6) & 7;
        const int rr = item >> 9;
        const int gq = l >> 4;
        const int z  = zt * 16 + (l & 15);
        u8s o;
        #pragma unroll
        for (int e = 0; e < 8; ++e)
            o[e] = f2bf(Msub[rr * 4096 + (gq * 8 + e) * 128 + z]);
        *(u8s*)(Mf + (((size_t)(r0 + rr) * 8 + zt) * 64 + l) * 8) = o;
    }
}

// ---------------- Kernel 2: INSTRUMENTATION — R13/R14 k_out body run 3x ------
// Pointers made opaque each pass (asm volatile) so every pass fully reloads
// frags and recomputes MFMA (no cross-pass CSE/DCE). Stores are idempotent ->
// output identical to single pass. Purpose: ~230 us dispatch lands in top-5
// WITH counters (MfmaUtil / VALUBusy / WRITE_SIZE / Occupancy for k_out).
__global__ __launch_bounds__(256, 3) void k_out3(
    const unsigned short* __restrict__ Bf, const unsigned short* __restrict__ Mf,
    const float* __restrict__ bo, float* __restrict__ out)
{
    const int r = blockIdx.x;
    const int t = threadIdx.x;
    const int l = t & 63, w = t >> 6;
    const int g = l >> 4, c16 = l & 15;
    const int n = r / LL;

    v4f bov[8];
    #pragma unroll
    for (int zt = 0; zt < 8; ++zt) bov[zt] = *(const v4f*)(bo + zt * 16 + g * 4);

    v4f* outv = (v4f*)(out + (size_t)r * LL * CZ);   // 32 v4f per j-row

    for (int rep = 0; rep < 3; ++rep) {
        // opaque the input pointers: forces full reload + recompute per pass
        unsigned long long pb = (unsigned long long)Bf;
        unsigned long long pm = (unsigned long long)Mf;
        asm volatile("" : "+v"(pb), "+v"(pm));
        const unsigned short* Bfo = (const unsigned short*)pb;
        const unsigned short* Mfo = (const unsigned short*)pm;

        s8v mf[8];
        {
            const s8v* Mfr = (const s8v*)(Mfo + (size_t)r * 8 * 64 * 8);
            #pragma unroll
            for (int zt = 0; zt < 8; ++zt) mf[zt] = Mfr[zt * 64 + l];
        }
        s8v af[6];
        {
            const s8v* Bfn = (const s8v*)(Bfo + (size_t)n * 24 * 64 * 8);
            #pragma unroll
            for (int i = 0; i < 6; ++i) af[i] = Bfn[(w + i * 4) * 64 + l];
        }

        #pragma unroll
        for (int i = 0; i < 6; ++i) {
            const int jt = w + i * 4;
            v4f* p = outv + (size_t)(jt * 16 + c16) * 32 + g;
            #pragma unroll
            for (int zt = 0; zt < 8; ++zt) {
                v4f d = __builtin_amdgcn_mfma_f32_16x16x32_bf16(mf[zt], af[i], (v4f)(0.f), 0, 0, 0);
                p[zt * 4] = d + bov[zt];
            }
        }
    }
}

extern "C" void kernel_launch(void* const* d_in, const int* in_sizes, int n_in,
                              void* d_out, int out_size, void* d_ws, size_t ws_size,
                              hipStream_t stream) {
    const float* s  = (const float*)d_in[0];
    const float* g  = (const float*)d_in[1];
    const float* be = (const float*)d_in[2];
    const float* W1 = (const float*)d_in[3];
    const float* b1 = (const float*)d_in[4];
    const float* W2 = (const float*)d_in[5];
    const float* b2 = (const float*)d_in[6];
    const float* Wo = (const float*)d_in[7];
    const float* bo = (const float*)d_in[8];
    float* out = (float*)d_out;

    // ws layout (bytes): Bf bf16 [0, 98304) | Mf bf16 [98304, +12582912)
    if (ws_size < 98304u + 12582912u) return;  // fail visibly, no UB
    unsigned short* Bf = (unsigned short*)d_ws;
    unsigned short* Mf = (unsigned short*)((char*)d_ws + 98304);

    k_prep<<<NL / 4, 256, 0, stream>>>(s, g, be, W1, b1, W2, b2, Wo, Bf, Mf);
    k_out3<<<NL, 256, 0, stream>>>(Bf, Mf, bo, out);
}

// Round 16
// 85.642 us; speedup vs baseline: 2.2838x; 2.2838x over previous
//
#include <hip/hip_runtime.h>
#include <hip/hip_bf16.h>

#define CS 384
#define CH 32
#define CZ 128
#define LL 384
#define NL 1536   // N*L
#define EPS 1e-5f

typedef float v4f __attribute__((ext_vector_type(4)));
typedef short s8v __attribute__((ext_vector_type(8)));          // 8 bf16 (MFMA A/B frag)
typedef unsigned short u8s __attribute__((ext_vector_type(8))); // 8 bf16 bits

static __device__ __forceinline__ unsigned short f2bf(float x) {
    unsigned int b = __float_as_uint(x);
    b += 0x7FFFu + ((b >> 16) & 1u);        // round-to-nearest-even
    return (unsigned short)(b >> 16);
}

// ---------------- Kernel 1: fused LN + matvec + pack Bf + M=A@Wo + pack Mf ---
// (identical to R14)
__global__ __launch_bounds__(256, 2) void k_prep(
    const float* __restrict__ s, const float* __restrict__ g, const float* __restrict__ be,
    const float* __restrict__ W1, const float* __restrict__ pb1,
    const float* __restrict__ W2, const float* __restrict__ pb2,
    const float* __restrict__ Wo,
    unsigned short* __restrict__ Bf, unsigned short* __restrict__ Mf)
{
    const int blk = blockIdx.x;     // 0..383
    const int r0  = blk * 4;
    const int t   = threadIdx.x;

    __shared__ float sn[4][392];
    __shared__ float Afl[4][CH];
    __shared__ __align__(16) float Msub[4 * 32 * 128];   // 64 KB

    // ---- Phase A: LayerNorm, wave w = row r0+w ----
    {
        const int w = t >> 6, lane = t & 63;
        const float* srow = s + (size_t)(r0 + w) * CS;
        float x[6];
        #pragma unroll
        for (int k = 0; k < 6; ++k) x[k] = srow[lane + k * 64];
        float p = x[0] + x[1] + x[2] + x[3] + x[4] + x[5];
        #pragma unroll
        for (int m = 1; m < 64; m <<= 1) p += __shfl_xor(p, m);
        const float mu = p * (1.0f / CS);
        float q = 0.f;
        #pragma unroll
        for (int k = 0; k < 6; ++k) { float d = x[k] - mu; q += d * d; }
        #pragma unroll
        for (int m = 1; m < 64; m <<= 1) q += __shfl_xor(q, m);
        const float rstd = rsqrtf(q * (1.0f / CS) + EPS);
        #pragma unroll
        for (int k = 0; k < 6; ++k) {
            const int c = lane + k * 64;
            sn[w][c] = (x[k] - mu) * rstd * g[c] + be[c];
        }
    }
    __syncthreads();

    // ---- Phase B: matvec, one output per thread ----
    {
        const int h = t & 31, mat = (t >> 5) & 1, rw = t >> 6;
        const float* W = mat ? W2 : W1;
        const float* snr = sn[rw];
        float acc = 0.f;
        #pragma unroll 8
        for (int c = 0; c < CS; ++c)
            acc += snr[c] * W[c * CH + h];
        acc += mat ? pb2[h] : pb1[h];
        if (!mat) {
            Afl[rw][h] = acc;
        } else {
            const int row = r0 + rw;
            const int n = row / LL, jr = row % LL;
            const int jt = jr >> 4, l16 = jr & 15;
            Bf[(((size_t)(n * 24 + jt)) * 64 + l16 + 16 * (h >> 3)) * 8 + (h & 7)] = f2bf(acc);
        }
    }
    __syncthreads();

    // ---- Phase C: M = Afl @ Wo ----
    const v4f* Wo4 = (const v4f*)Wo;       // 1024 v4f per c-row
    #pragma unroll
    for (int it = 0; it < 4; ++it) {
        const int col = t + it * 256;      // col = d*32 + zq
        v4f acc[4];
        #pragma unroll
        for (int r = 0; r < 4; ++r) acc[r] = (v4f)(0.f);
        #pragma unroll 8
        for (int c = 0; c < CH; ++c) {
            const v4f wv = Wo4[(size_t)c * 1024 + col];
            #pragma unroll
            for (int r = 0; r < 4; ++r)
                acc[r] += Afl[r][c] * wv;
        }
        #pragma unroll
        for (int r = 0; r < 4; ++r)
            *((v4f*)&Msub[r * 4096 + col * 4]) = acc[r];   // flat = r*4096 + d*128 + zq*4
    }
    __syncthreads();

    #pragma unroll
    for (int i = 0; i < 8; ++i) {
        const int item = t + i * 256;          // 0..2047
        const int l  = item & 63;
        const int zt = (item >> 6) & 7;
        const int rr = item >> 9;
        const int gq = l >> 4;
        const int z  = zt * 16 + (l & 15);
        u8s o;
        #pragma unroll
        for (int e = 0; e < 8; ++e)
            o[e] = f2bf(Msub[rr * 4096 + (gq * 8 + e) * 128 + z]);
        *(u8s*)(Mf + (((size_t)(r0 + rr) * 8 + zt) * 64 + l) * 8) = o;
    }
}

// ---------------- Kernel 2: MFMA k_out with LDS-bounce contiguous stores -----
// Block = r (256 thr, 4 waves). Wave w: j-tiles {w, w+4, ...} (6) x 8 z-tiles.
// Frags hoisted (R13). NEW: per jt, D frags (+bias) bounce through a per-wave
// 8 KB LDS region (XOR-swizzled, both directions 8-cyc minimum) and are stored
// as 8 CONTIGUOUS 1024-B wave-stores (fill-kernel byte pattern) instead of
// 16x64-B scattered segments.
__global__ __launch_bounds__(256, 3) void k_out(
    const unsigned short* __restrict__ Bf, const unsigned short* __restrict__ Mf,
    const float* __restrict__ bo, float* __restrict__ out)
{
    const int r = blockIdx.x;
    const int t = threadIdx.x;
    const int l = t & 63, w = t >> 6;
    const int g = l >> 4, c16 = l & 15;
    const int li = l & 31, hi2 = l >> 5;
    const int n = r / LL;

    __shared__ __align__(16) float lds[4][2048];   // 8 KB per wave

    s8v mf[8];
    {
        const s8v* Mfr = (const s8v*)(Mf + (size_t)r * 8 * 64 * 8);
        #pragma unroll
        for (int zt = 0; zt < 8; ++zt) mf[zt] = Mfr[zt * 64 + l];
    }
    s8v af[6];
    {
        const s8v* Bfn = (const s8v*)(Bf + (size_t)n * 24 * 64 * 8);
        #pragma unroll
        for (int i = 0; i < 6; ++i) af[i] = Bfn[(w + i * 4) * 64 + l];
    }
    v4f bov[8];
    #pragma unroll
    for (int zt = 0; zt < 8; ++zt) bov[zt] = *(const v4f*)(bo + zt * 16 + g * 4);

    char* myl = (char*)lds[w];
    v4f* outv = (v4f*)(out + (size_t)r * LL * CZ);   // 32 v4f per j-row

    #pragma unroll
    for (int i = 0; i < 6; ++i) {
        const int jt = w + i * 4;

        // MFMA + bias -> LDS (swizzled write: start banks cover all 32)
        #pragma unroll
        for (int zt = 0; zt < 8; ++zt) {
            v4f d = __builtin_amdgcn_mfma_f32_16x16x32_bf16(mf[zt], af[i], (v4f)(0.f), 0, 0, 0);
            d += bov[zt];
            const int byte = (c16 << 9) + (((zt << 6) + (g << 4)) ^ ((c16 & 7) << 4));
            *(v4f*)(myl + byte) = d;
        }
        asm volatile("s_waitcnt lgkmcnt(0)" ::: "memory");

        // contiguous read-back + contiguous 1024-B wave-stores
        #pragma unroll
        for (int i2 = 0; i2 < 8; ++i2) {
            const int rr = 2 * i2 + hi2;
            const int byte = (rr << 9) + (((li << 4)) ^ ((rr & 7) << 4));
            const v4f v = *(const v4f*)(myl + byte);
            outv[(size_t)(jt * 16 + rr) * 32 + li] = v;
        }
    }
}

extern "C" void kernel_launch(void* const* d_in, const int* in_sizes, int n_in,
                              void* d_out, int out_size, void* d_ws, size_t ws_size,
                              hipStream_t stream) {
    const float* s  = (const float*)d_in[0];
    const float* g  = (const float*)d_in[1];
    const float* be = (const float*)d_in[2];
    const float* W1 = (const float*)d_in[3];
    const float* b1 = (const float*)d_in[4];
    const float* W2 = (const float*)d_in[5];
    const float* b2 = (const float*)d_in[6];
    const float* Wo = (const float*)d_in[7];
    const float* bo = (const float*)d_in[8];
    float* out = (float*)d_out;

    // ws layout (bytes): Bf bf16 [0, 98304) | Mf bf16 [98304, +12582912)
    if (ws_size < 98304u + 12582912u) return;  // fail visibly, no UB
    unsigned short* Bf = (unsigned short*)d_ws;
    unsigned short* Mf = (unsigned short*)((char*)d_ws + 98304);

    k_prep<<<NL / 4, 256, 0, stream>>>(s, g, be, W1, b1, W2, b2, Wo, Bf, Mf);
    k_out <<<NL, 256, 0, stream>>>(Bf, Mf, bo, out);
}